// Round 11
// baseline (22.772 us; speedup 1.0000x reference)
//
#include <hip/hip_runtime.h>

// out[i] = MLP(emb_user[uid[i]]) + MLP(emb_movie[mid[i]])
// MLP: relu(x@W1+b1) -> relu(@W2+b2) -> @W3+b3.  Single kernel, 32x32x16
// bf16 MFMA, fp32 acc, sigma-permuted W1 (register-only layer1->layer2
// handoff, validated r4-r10).
//
// Round-11: COOPERATIVE 256-B BURST GATHERS + TWO-PASS PIPELINE.
//  - Per wave, 32 embedding rows are staged into a wave-private 8KB LDS
//    region by 8 global_load_lds dwordx4 ops: each op moves 4 CONTIGUOUS
//    256-B rows (vs 64 scattered 16-B accesses per op before) -> DRAM-burst
//    friendly, 10x fewer transactions.
//  - XOR swizzle (rule #21: linear LDS dest, pre-swizzled GLOBAL source,
//    swizzled read): row r byte q lives at r*256 + (q ^ ((r&7)<<4)) ->
//    b128 read-back at the 4-way bank floor instead of 32-way conflict.
//  - Pipeline: user rows staged first (drained once, right after the
//    weight barrier); movie rows reuse the same LDS region, issued after
//    the user reads retire, and fly under the whole user MLP pass.
//  - All waits are vmcnt(0)/lgkmcnt(0) (no fragile counted waits); barrier
//    is R10's lgkm-only s_barrier (does NOT drain vmcnt).
// LDS: w1f 32KB + w2f 64KB + rowbuf 64KB = 160KB (1 block/CU).
// 512 thr = 8 waves x 32 samples.  Grid 256.  2 waves/SIMD.

typedef __attribute__((ext_vector_type(8))) short bf16x8;
typedef __attribute__((ext_vector_type(16))) float f32x16;

__device__ __forceinline__ unsigned int cvt_pk(float lo, float hi) {
  unsigned int r;
  asm("v_cvt_pk_bf16_f32 %0, %1, %2" : "=v"(r) : "v"(lo), "v"(hi));
  return r;  // bf16(lo) in [15:0], bf16(hi) in [31:16], RNE
}

__global__ __launch_bounds__(512, 2) void movielens_mlp(
    const int* __restrict__ uids, const int* __restrict__ mids,
    const float* __restrict__ EU, const float* __restrict__ EM,
    const float* __restrict__ W1, const float* __restrict__ B1,
    const float* __restrict__ W2, const float* __restrict__ B2,
    const float* __restrict__ W3, const float* __restrict__ B3,
    float* __restrict__ out) {
  __shared__ __align__(16) unsigned short w1f[32 * 512];  // 32 KB
  __shared__ __align__(16) unsigned short w2f[64 * 512];  // 64 KB
  __shared__ __align__(16) char rowbuf[8 * 8192];         // 64 KB

  const int tid = threadIdx.x;
  const int lane = tid & 63, wv = tid >> 6;
  const int m32 = lane & 31, H = lane >> 5;
  const int h4 = lane >> 4, o16 = lane & 15;  // glds lane geometry
  const int sbase = blockIdx.x * 256 + wv * 32;

  // ---- idx loads for the per-instruction row groups (4 rows/op) ----
  int us[8], ms[8];
#pragma unroll
  for (int i = 0; i < 8; ++i) {
    us[i] = uids[sbase + 4 * i + h4];
    ms[i] = mids[sbase + 4 * i + h4];
  }

  // staging unit geometry (validated r8-r10)
  const int cq = tid & 7, bb = (tid >> 3) & 1, hh = (tid >> 4) & 1;

  // ---- weight loads (no deps; fly while idx resolves) ----
  float4 wr[6][4];
#pragma unroll
  for (int i = 0; i < 2; ++i) {  // W1 units
    const int fi = (tid >> 5) + 16 * i;  // 0..31 = ct*4+kk
    const int ct = fi >> 2, kk = fi & 3;
    const float* s = W1 + (16 * kk + 8 * hh + 4 * bb) * 256 + 32 * ct + 4 * cq;
    wr[i][0] = *(const float4*)(s);
    wr[i][1] = *(const float4*)(s + 256);
    wr[i][2] = *(const float4*)(s + 512);
    wr[i][3] = *(const float4*)(s + 768);
  }
#pragma unroll
  for (int i = 2; i < 6; ++i) {  // W2 units
    const int f2 = (tid >> 5) + 16 * (i - 2);  // 0..63 = ks*4+n2
    const int ks = f2 >> 2, n2 = f2 & 3;
    const float* s = W2 + (16 * ks + 8 * hh + 4 * bb) * 128 + 32 * n2 + 4 * cq;
    wr[i][0] = *(const float4*)(s);
    wr[i][1] = *(const float4*)(s + 128);
    wr[i][2] = *(const float4*)(s + 256);
    wr[i][3] = *(const float4*)(s + 384);
  }

  // ---- USER burst-gather: 8 x global_load_lds, 4 contiguous rows each ----
  // LDS[r*256 + x] = row_r[x ^ ((r&7)<<4)]  (source pre-swizzled, dest linear)
  char* const myrows = rowbuf + wv * 8192;
#pragma unroll
  for (int i = 0; i < 8; ++i) {
    const int swz = (o16 * 16) ^ ((4 * (i & 1) + h4) << 4);
    const char* src = (const char*)EU + (size_t)us[i] * 256 + swz;
    __builtin_amdgcn_global_load_lds(
        (const __attribute__((address_space(1))) unsigned int*)src,
        (__attribute__((address_space(3))) unsigned int*)(myrows + i * 1024),
        16, 0, 0);
  }
  __builtin_amdgcn_sched_barrier(0);

  // ---- stage W1 (sigma-permuted) + W2 into fragment order ----
  const int w1slot0 = 32 * hh + 16 * (cq >> 2) + 8 * (cq & 1) + 4 * ((cq >> 1) & 1);
#pragma unroll
  for (int i = 0; i < 2; ++i) {
    const int fi = (tid >> 5) + 16 * i;
    const float c0[4] = {wr[i][0].x, wr[i][0].y, wr[i][0].z, wr[i][0].w};
    const float c1[4] = {wr[i][1].x, wr[i][1].y, wr[i][1].z, wr[i][1].w};
    const float c2[4] = {wr[i][2].x, wr[i][2].y, wr[i][2].z, wr[i][2].w};
    const float c3[4] = {wr[i][3].x, wr[i][3].y, wr[i][3].z, wr[i][3].w};
#pragma unroll
    for (int s = 0; s < 4; ++s) {
      uint2 pk;
      pk.x = cvt_pk(c0[s], c1[s]);
      pk.y = cvt_pk(c2[s], c3[s]);
      *(uint2*)&w1f[fi * 512 + (w1slot0 + s) * 8 + 4 * bb] = pk;
    }
  }
#pragma unroll
  for (int i = 2; i < 6; ++i) {
    const int f2 = (tid >> 5) + 16 * (i - 2);
    const int slot0 = 32 * hh + 4 * cq;
    const float c0[4] = {wr[i][0].x, wr[i][0].y, wr[i][0].z, wr[i][0].w};
    const float c1[4] = {wr[i][1].x, wr[i][1].y, wr[i][1].z, wr[i][1].w};
    const float c2[4] = {wr[i][2].x, wr[i][2].y, wr[i][2].z, wr[i][2].w};
    const float c3[4] = {wr[i][3].x, wr[i][3].y, wr[i][3].z, wr[i][3].w};
#pragma unroll
    for (int s = 0; s < 4; ++s) {
      uint2 pk;
      pk.x = cvt_pk(c0[s], c1[s]);
      pk.y = cvt_pk(c2[s], c3[s]);
      *(uint2*)&w2f[f2 * 512 + (slot0 + s) * 8 + 4 * bb] = pk;
    }
  }

  // ---- lgkm-only barrier (R10): does NOT drain vmcnt ----
  asm volatile("s_waitcnt lgkmcnt(0)\n\ts_barrier" ::: "memory");
  __builtin_amdgcn_sched_barrier(0);
  // user glds are the youngest VMEM issued; weights already consumed.
  asm volatile("s_waitcnt vmcnt(0)" ::: "memory");
  __builtin_amdgcn_sched_barrier(0);

  // ---- user rows -> layer-1 B-frags (swizzled b128 reads) ----
  const int rsw = (m32 & 7) << 4;
  bf16x8 xfu[4];
#pragma unroll
  for (int kk = 0; kk < 4; ++kk) {
    const int q0 = 64 * kk + 32 * H;
    const float4 a = *(const float4*)(myrows + m32 * 256 + (q0 ^ rsw));
    const float4 b = *(const float4*)(myrows + m32 * 256 + ((q0 + 16) ^ rsw));
    uint4 w;
    w.x = cvt_pk(a.x, a.y);
    w.y = cvt_pk(a.z, a.w);
    w.z = cvt_pk(b.x, b.y);
    w.w = cvt_pk(b.z, b.w);
    xfu[kk] = __builtin_bit_cast(bf16x8, w);
  }
  // retire the user ds_reads before movie glds may overwrite the region
  __builtin_amdgcn_sched_barrier(0);
  asm volatile("s_waitcnt lgkmcnt(0)" ::: "memory");
  __builtin_amdgcn_sched_barrier(0);

  // ---- MOVIE burst-gather into the same region (flies under user pass) ----
#pragma unroll
  for (int i = 0; i < 8; ++i) {
    const int swz = (o16 * 16) ^ ((4 * (i & 1) + h4) << 4);
    const char* src = (const char*)EM + (size_t)ms[i] * 256 + swz;
    __builtin_amdgcn_global_load_lds(
        (const __attribute__((address_space(1))) unsigned int*)src,
        (__attribute__((address_space(3))) unsigned int*)(myrows + i * 1024),
        16, 0, 0);
  }
  __builtin_amdgcn_sched_barrier(0);

  // ---- one full MLP pass (layers 1-3) for 32 samples (validated r9) ----
  auto run_pass = [&](const bf16x8 xf[4]) -> float {
    f32x16 acc2[4];
#pragma unroll
    for (int n2 = 0; n2 < 4; ++n2)
#pragma unroll
      for (int rq = 0; rq < 4; ++rq) {
        const float4 bq = *(const float4*)(B2 + 32 * n2 + 8 * rq + 4 * H);
        acc2[n2][4 * rq + 0] = bq.x;
        acc2[n2][4 * rq + 1] = bq.y;
        acc2[n2][4 * rq + 2] = bq.z;
        acc2[n2][4 * rq + 3] = bq.w;
      }
    bf16x8 a1[4];
#pragma unroll
    for (int kk = 0; kk < 4; ++kk)
      a1[kk] = *(const bf16x8*)&w1f[kk * 512 + lane * 8];

#pragma unroll
    for (int ct = 0; ct < 8; ++ct) {
      const float4 q0 = *(const float4*)(B1 + 32 * ct + 8 * H);
      const float4 q1 = *(const float4*)(B1 + 32 * ct + 8 * H + 4);
      const float4 q2 = *(const float4*)(B1 + 32 * ct + 8 * H + 16);
      const float4 q3 = *(const float4*)(B1 + 32 * ct + 8 * H + 20);
      f32x16 acc1;
      acc1[0] = q0.x;  acc1[1] = q0.y;  acc1[2] = q0.z;  acc1[3] = q0.w;
      acc1[4] = q1.x;  acc1[5] = q1.y;  acc1[6] = q1.z;  acc1[7] = q1.w;
      acc1[8] = q2.x;  acc1[9] = q2.y;  acc1[10] = q2.z; acc1[11] = q2.w;
      acc1[12] = q3.x; acc1[13] = q3.y; acc1[14] = q3.z; acc1[15] = q3.w;
#pragma unroll
      for (int kk = 0; kk < 4; ++kk)
        acc1 = __builtin_amdgcn_mfma_f32_32x32x16_bf16(a1[kk], xf[kk], acc1, 0, 0, 0);

      uint4 lo, hi;
      lo.x = cvt_pk(fmaxf(acc1[0], 0.f), fmaxf(acc1[1], 0.f));
      lo.y = cvt_pk(fmaxf(acc1[2], 0.f), fmaxf(acc1[3], 0.f));
      lo.z = cvt_pk(fmaxf(acc1[4], 0.f), fmaxf(acc1[5], 0.f));
      lo.w = cvt_pk(fmaxf(acc1[6], 0.f), fmaxf(acc1[7], 0.f));
      hi.x = cvt_pk(fmaxf(acc1[8], 0.f), fmaxf(acc1[9], 0.f));
      hi.y = cvt_pk(fmaxf(acc1[10], 0.f), fmaxf(acc1[11], 0.f));
      hi.z = cvt_pk(fmaxf(acc1[12], 0.f), fmaxf(acc1[13], 0.f));
      hi.w = cvt_pk(fmaxf(acc1[14], 0.f), fmaxf(acc1[15], 0.f));

      if (ct < 7) {  // prefetch next chunk's W1 frags under layer-2 MFMAs
#pragma unroll
        for (int kk = 0; kk < 4; ++kk)
          a1[kk] = *(const bf16x8*)&w1f[((ct + 1) * 4 + kk) * 512 + lane * 8];
      }

#pragma unroll
      for (int q = 0; q < 4; ++q) {
        const bf16x8 wlo = *(const bf16x8*)&w2f[(8 * ct + q) * 512 + lane * 8];
        acc2[q] = __builtin_amdgcn_mfma_f32_32x32x16_bf16(
            wlo, __builtin_bit_cast(bf16x8, lo), acc2[q], 0, 0, 0);
      }
#pragma unroll
      for (int q = 0; q < 4; ++q) {
        const bf16x8 whi = *(const bf16x8*)&w2f[(8 * ct + 4 + q) * 512 + lane * 8];
        acc2[q] = __builtin_amdgcn_mfma_f32_32x32x16_bf16(
            whi, __builtin_bit_cast(bf16x8, hi), acc2[q], 0, 0, 0);
      }
    }

    float part = 0.f;
#pragma unroll
    for (int n2 = 0; n2 < 4; ++n2)
#pragma unroll
      for (int rq = 0; rq < 4; ++rq) {
        const float4 wq = *(const float4*)(W3 + 32 * n2 + 8 * rq + 4 * H);
        part += fmaxf(acc2[n2][4 * rq + 0], 0.f) * wq.x +
                fmaxf(acc2[n2][4 * rq + 1], 0.f) * wq.y +
                fmaxf(acc2[n2][4 * rq + 2], 0.f) * wq.z +
                fmaxf(acc2[n2][4 * rq + 3], 0.f) * wq.w;
      }
    return part;
  };

  // ---- USER pass (movie bursts in flight underneath) ----
  const float part_u = run_pass(xfu);

  // ---- drain movie bursts, convert, movie pass ----
  __builtin_amdgcn_sched_barrier(0);
  asm volatile("s_waitcnt vmcnt(0)" ::: "memory");
  __builtin_amdgcn_sched_barrier(0);

  bf16x8 xfm[4];
#pragma unroll
  for (int kk = 0; kk < 4; ++kk) {
    const int q0 = 64 * kk + 32 * H;
    const float4 a = *(const float4*)(myrows + m32 * 256 + (q0 ^ rsw));
    const float4 b = *(const float4*)(myrows + m32 * 256 + ((q0 + 16) ^ rsw));
    uint4 w;
    w.x = cvt_pk(a.x, a.y);
    w.y = cvt_pk(a.z, a.w);
    w.z = cvt_pk(b.x, b.y);
    w.w = cvt_pk(b.z, b.w);
    xfm[kk] = __builtin_bit_cast(bf16x8, w);
  }
  const float part_m = run_pass(xfm);

  // ---- combine across H-halves and store ----
  float part = part_u + part_m;
  part += __shfl_xor(part, 32, 64);
  if (lane < 32) out[sbase + lane] = part + 2.f * B3[0];
}

extern "C" void kernel_launch(void* const* d_in, const int* in_sizes, int n_in,
                              void* d_out, int out_size, void* d_ws, size_t ws_size,
                              hipStream_t stream) {
  const int* uids = (const int*)d_in[0];
  const int* mids = (const int*)d_in[1];
  const float* EU = (const float*)d_in[2];
  const float* EM = (const float*)d_in[3];
  const float* W1 = (const float*)d_in[4];
  const float* B1 = (const float*)d_in[5];
  const float* W2 = (const float*)d_in[6];
  const float* B2 = (const float*)d_in[7];
  const float* W3 = (const float*)d_in[8];
  const float* B3 = (const float*)d_in[9];
  float* out = (float*)d_out;

  const int B = in_sizes[0];  // 65536
  const int nblk = B / 256;   // 256 blocks x 256 samples
  hipLaunchKernelGGL(movielens_mlp, dim3(nblk), dim3(512), 0, stream,
                     uids, mids, EU, EM, W1, B1, W2, B2, W3, B3, out);
}